// Round 10
// baseline (100.022 us; speedup 1.0000x reference)
//
#include <hip/hip_runtime.h>

// SlayerNet SNN forward, MI355X.
// y1t = w1@x [k_mm1: 16 wave-uniform c-groups, scalar-pipe weights, float2/lane] ;
// pot1 = FIR129(y1t) [k_fir1] ; s1 = scan [bits] ;
// pot2 = FIR129(w2@s1) [linearity swap] ; s2 = scan -> d_out (fp32).
// Spike scans: speculative block-parallel + exact fixup (state = last 15 spike
// bits; 15-bit mask match => bitwise-exact state).

#define T_LEN   65536
#define NCH     250
#define NO1     25
#define KTAPS   129      // taps d=0..128, eps[d] = srm[128-d]
#define PAD     128
#define SRM_LEN 257
#define REF_LEN 16
#define THETA_F 10.0f
#define LBLK    128      // scan block length (== 4 x 32-bit words)
#define NBK     512      // NBK*LBLK == T_LEN
#define WARM    128      // speculative warm-up steps
#define TS      256      // pot2 tile size
#define TT      128      // mm1 time-tile (y1t tile width)
#define FTILE   1024     // fir1 tile
#define NWORDS  (T_LEN / 32)
#define NGRP    16       // mm1 channel groups (wave-uniform)

// One gen_spikes step. fma(s,rn,b) is bit-exact vs fadd(b,fmul(s,rn)):
// s in {0,1} makes the product exact, so single rounding = same rounding.
__device__ __forceinline__ void srm_step(float p, const float (&rn)[15], float (&b)[15],
                                         unsigned &m, float &sf_out) {
  float u = p + b[0];
  unsigned sp = (u >= THETA_F) ? 1u : 0u;
  float sf = sp ? 1.0f : 0.0f;
#pragma unroll
  for (int j = 0; j < 14; ++j) b[j] = __builtin_fmaf(sf, rn[j], b[j + 1]);
  b[14] = __fmul_rn(sf, rn[14]);
  m = (m << 1) | sp;
  sf_out = sf;
}

__global__ void k_fill(float* out, float v) {
  out[blockIdx.x * 256 + threadIdx.x] = v;
}

// transpose w1 (25x250) -> w1T (250x25) so per-channel weights are contiguous
__global__ __launch_bounds__(256) void k_prep(const float* __restrict__ w1,
                                              float* __restrict__ w1T) {
  for (int i = threadIdx.x; i < NO1 * NCH; i += 256) {
    int c = i / NO1, o = i - c * NO1;
    w1T[i] = w1[o * NCH + c];
  }
}

// K1: y1t[tile][o][p] = sum_c w1[o,c]*x[c][tile*TT+p].
// 1024 threads = 16 waves; wave g owns a contiguous channel group
// (10 groups of 16, 6 of 15); each lane holds a float2 of positions
// (acc[25][2] = 50 VGPR -> no spill). Weights via wave-uniform scalar loads.
// Fold 16 partials via LDS in 5 o-chunks, left-to-right (same order as R9).
__global__ __launch_bounds__(1024, 4) void k_mm1(const float* __restrict__ x,
                                                 const float* __restrict__ w1T,
                                                 float* __restrict__ y1t) {
  __shared__ __align__(16) float part[NGRP][5][TT];  // 40 KB
  const int tid = threadIdx.x;
  const int lane = tid & 63;
  const int wv = __builtin_amdgcn_readfirstlane(tid >> 6);  // wave id, SGPR
  const int t0 = blockIdx.x * TT;
  const int cs = wv * 15 + (wv < 10 ? wv : 10);   // group start (same as R9)
  const int cn = (wv < 10) ? 16 : 15;             // group size
  float acc[NO1][2];
#pragma unroll
  for (int o = 0; o < NO1; ++o) { acc[o][0] = 0.f; acc[o][1] = 0.f; }
  const float* xp = x + (size_t)cs * T_LEN + t0 + lane * 2;
  const float* wt = w1T + cs * NO1;               // SGPR base
  float2 xb0 = *(const float2*)xp;
  float2 xb1 = *(const float2*)(xp + T_LEN);
  for (int ci = 0; ci < cn; ++ci) {
    float2 xv = xb0;
    xb0 = xb1;
    xb1 = (ci + 2 < cn) ? *(const float2*)(xp + (size_t)(ci + 2) * T_LEN)
                        : make_float2(0.f, 0.f);
    const float* wr = wt + ci * NO1;              // uniform -> s_load batch
#pragma unroll
    for (int o = 0; o < NO1; ++o) {
      float wvv = wr[o];
      acc[o][0] = __builtin_fmaf(wvv, xv.x, acc[o][0]);
      acc[o][1] = __builtin_fmaf(wvv, xv.y, acc[o][1]);
    }
  }
  // fold in 5 rounds of 5 outputs each; left-to-right over 16 groups
  float* yb = y1t + (size_t)blockIdx.x * (NO1 * TT);
#pragma unroll
  for (int r = 0; r < 5; ++r) {
#pragma unroll
    for (int oo = 0; oo < 5; ++oo) {
      int o = r * 5 + oo;
      *(float2*)&part[wv][oo][lane * 2] = make_float2(acc[o][0], acc[o][1]);
    }
    __syncthreads();
    if (tid < 5 * (TT / 4)) {   // 160 fold threads
      int oo = tid >> 5;
      int p4 = (tid & 31) * 4;
      float4 s = *(const float4*)&part[0][oo][p4];
#pragma unroll
      for (int g = 1; g < NGRP; ++g) {
        float4 p = *(const float4*)&part[g][oo][p4];
        s.x = __fadd_rn(s.x, p.x);
        s.y = __fadd_rn(s.y, p.y);
        s.z = __fadd_rn(s.z, p.z);
        s.w = __fadd_rn(s.w, p.w);
      }
      *(float4*)&yb[(r * 5 + oo) * TT + p4] = s;
    }
    __syncthreads();
  }
}

// K2: pot1[o][t] = sum_d eps[d]*y1[o][t-d]; y1 in tiled layout [tile][o][TT].
__global__ __launch_bounds__(256, 8) void k_fir1(const float* __restrict__ y1t,
                                                 const float* __restrict__ srm,
                                                 float* __restrict__ pot1) {
  __shared__ __align__(16) float win[FTILE + PAD];
  const int tid = threadIdx.x;
  const int o = blockIdx.y;
  const int t0 = blockIdx.x * FTILE;
  for (int j = tid; j < FTILE + PAD; j += 256) {
    int g = t0 - PAD + j;
    win[j] = (g >= 0)
        ? y1t[(size_t)(g >> 7) * (NO1 * TT) + o * TT + (g & (TT - 1))] : 0.0f;
  }
  __syncthreads();
  const int base = tid * 4;
  float q0 = 0.0f, q1 = 0.0f, q2 = 0.0f, q3 = 0.0f;
  // i descending => per-output tap order d ascending (proven ordering).
#pragma unroll
  for (int i = 32; i >= 0; --i) {
    float4 v = *(const float4*)&win[base + 4 * i];
#pragma unroll
    for (int l = 3; l >= 0; --l) {
      float vl = (l == 0) ? v.x : (l == 1) ? v.y : (l == 2) ? v.z : v.w;
#pragma unroll
      for (int k = 0; k < 4; ++k) {
        int d = 128 + k - 4 * i - l;
        if (d >= 0 && d <= 128) {
          float e = srm[4 * i + l - k];  // uniform -> scalar load
          if (k == 0) q0 = __builtin_fmaf(e, vl, q0);
          else if (k == 1) q1 = __builtin_fmaf(e, vl, q1);
          else if (k == 2) q2 = __builtin_fmaf(e, vl, q2);
          else q3 = __builtin_fmaf(e, vl, q3);
        }
      }
    }
  }
  *(float4*)&pot1[(size_t)o * T_LEN + t0 + base] = make_float4(q0, q1, q2, q3);
}

// K5: pot2 = FIR129( z ),  z[t] = sum_o w2[o] * s1[o][t]  (bit-packed s1).
__global__ __launch_bounds__(TS) void k_pot2(const unsigned* __restrict__ s1p,
                                             const float* __restrict__ srm,
                                             const float* __restrict__ w2,
                                             float* __restrict__ pot2) {
  __shared__ float zs[TS + PAD];
  const int tid = threadIdx.x;
  const int t0 = blockIdx.x * TS;
  const int g0 = t0 - PAD;
  {
    int g = g0 + tid;
    float z = 0.0f;
    if (g >= 0) {
      int wi = g >> 5, sh = g & 31;
#pragma unroll
      for (int o = 0; o < NO1; ++o) {
        unsigned wvv = s1p[o * NWORDS + wi];
        z += ((wvv >> sh) & 1u) ? w2[o] : 0.0f;
      }
    }
    zs[tid] = z;
    if (tid < PAD) {
      int g2 = g0 + TS + tid;
      int wi = g2 >> 5, sh = g2 & 31;
      float z2 = 0.0f;
#pragma unroll
      for (int o = 0; o < NO1; ++o) {
        unsigned wvv = s1p[o * NWORDS + wi];
        z2 += ((wvv >> sh) & 1u) ? w2[o] : 0.0f;
      }
      zs[TS + tid] = z2;
    }
  }
  __syncthreads();
  float a = 0.0f;
#pragma unroll
  for (int d = 0; d < KTAPS; ++d) {
    float e = srm[PAD - d];
    a = __builtin_fmaf(e, zs[PAD + tid - d], a);
  }
  pot2[t0 + tid] = a;
}

// Speculative scan: one thread per (channel, block). WARM steps from assumed
// zero state, then LBLK emitted steps; records entry mask + exit mask/state.
template <int C, bool PACKED>
__global__ __launch_bounds__(64) void k_scan_spec(const float* __restrict__ pot,
                                                  const float* __restrict__ refk,
                                                  float* __restrict__ s,
                                                  unsigned* __restrict__ sp_,
                                                  unsigned* __restrict__ specin_m,
                                                  unsigned* __restrict__ specout_m,
                                                  float* __restrict__ specout_b) {
  int idx = blockIdx.x * 64 + threadIdx.x;
  if (idx >= C * NBK) return;
  int c = idx / NBK;
  int bb = idx - c * NBK;
  int tsr = bb * LBLK - WARM;
  float rn[15];
#pragma unroll
  for (int j = 0; j < 15; ++j) rn[j] = refk[j + 1];
  float b[15];
#pragma unroll
  for (int j = 0; j < 15; ++j) b[j] = 0.0f;
  unsigned m = 0;
  const float* prow = pot + (size_t)c * T_LEN;
  float* srow = PACKED ? nullptr : (s + (size_t)c * T_LEN);
  unsigned* srowp = PACKED ? (sp_ + (size_t)c * NWORDS) : nullptr;
  for (int k = 0; k < WARM + LBLK; k += 4) {
    if (k == WARM) specin_m[idx] = m & 0x7FFFu;
    int t = tsr + k;
    if (t < 0) continue;
    float4 pv = *(const float4*)(prow + t);
    float s0, s1v, s2, s3;
    srm_step(pv.x, rn, b, m, s0);
    srm_step(pv.y, rn, b, m, s1v);
    srm_step(pv.z, rn, b, m, s2);
    srm_step(pv.w, rn, b, m, s3);
    if (k >= WARM) {
      if (PACKED) {
        if (((t + 3) & 31) == 31) srowp[(t - 28) >> 5] = __brev(m);
      } else {
        *(float4*)(srow + t) = make_float4(s0, s1v, s2, s3);
      }
    }
  }
  specout_m[idx] = m & 0x7FFFu;
#pragma unroll
  for (int j = 0; j < 15; ++j) specout_b[idx * 16 + j] = b[j];
}

// Exact fixup: one WAVE per channel. All 8 mask-groups preloaded, ballot chain
// check => 64 blocks/iter fast path; mismatch path walks via shuffles.
template <int C, bool PACKED>
__global__ __launch_bounds__(64) void k_scan_fix(const float* __restrict__ pot,
                                                 const float* __restrict__ refk,
                                                 float* __restrict__ s,
                                                 unsigned* __restrict__ sp_,
                                                 const unsigned* __restrict__ specin_m,
                                                 const unsigned* __restrict__ specout_m,
                                                 const float* __restrict__ specout_b) {
  const int c = blockIdx.x;
  const int lane = threadIdx.x;
  float rn[15];
#pragma unroll
  for (int j = 0; j < 15; ++j) rn[j] = refk[j + 1];
  float b[15];
#pragma unroll
  for (int j = 0; j < 15; ++j) b[j] = 0.0f;
  unsigned m = 0;
  bool haveB = true;
  const float* prow = pot + (size_t)c * T_LEN;
  float* srow = PACKED ? nullptr : (s + (size_t)c * T_LEN);
  unsigned* srowp = PACKED ? (sp_ + (size_t)c * NWORDS) : nullptr;
  unsigned prev_last = 0;

  unsigned siv[NBK / 64], sov[NBK / 64];
#pragma unroll
  for (int g = 0; g < NBK / 64; ++g) {
    siv[g] = specin_m[c * NBK + g * 64 + lane];
    sov[g] = specout_m[c * NBK + g * 64 + lane];
  }
#pragma unroll
  for (int g = 0; g < NBK / 64; ++g) {
    const unsigned si = siv[g];
    const unsigned so = sov[g];
    unsigned so_prev = __shfl_up(so, 1);
    if (lane == 0) so_prev = prev_last;
    const unsigned long long flags = __ballot(si == so_prev);
    prev_last = __shfl(so, 63);
    const unsigned si0 = __shfl(si, 0);
    if (flags == ~0ull && (m & 0x7FFFu) == si0) {
      m = prev_last;
      haveB = false;
      continue;
    }
    for (int r = 0; r < 64; ++r) {
      const unsigned sir = __shfl(si, r);
      const unsigned sor = __shfl(so, r);
      if ((m & 0x7FFFu) == sir) {
        m = sor;
        haveB = false;
      } else {
        const int bbr = g * 64 + r;  // bbr>=1: block 0 entry mask 0 always matches
        if (!haveB) {
          const int pb = (c * NBK + bbr - 1) * 16;
#pragma unroll
          for (int q2 = 0; q2 < 15; ++q2) b[q2] = specout_b[pb + q2];
          haveB = true;
        }
        const int t0 = bbr * LBLK;
        for (int t = t0; t < t0 + LBLK; t += 4) {
          float4 pv = *(const float4*)(prow + t);
          float s0, s1v, s2, s3;
          srm_step(pv.x, rn, b, m, s0);
          srm_step(pv.y, rn, b, m, s1v);
          srm_step(pv.z, rn, b, m, s2);
          srm_step(pv.w, rn, b, m, s3);
          if (PACKED) {
            if ((((t + 3) & 31) == 31) && lane == 0) srowp[(t - 28) >> 5] = __brev(m);
          } else {
            if (lane == 0) *(float4*)(srow + t) = make_float4(s0, s1v, s2, s3);
          }
        }
        haveB = true;
      }
    }
  }
}

extern "C" void kernel_launch(void* const* d_in, const int* in_sizes, int n_in,
                              void* d_out, int out_size, void* d_ws, size_t ws_size,
                              hipStream_t stream) {
  const float* x    = (const float*)d_in[0];  // 250*65536
  const float* srm  = (const float*)d_in[1];  // 257
  const float* refk = (const float*)d_in[2];  // 16
  const float* w1   = (const float*)d_in[3];  // 25*250
  const float* w2   = (const float*)d_in[4];  // 25
  float* out = (float*)d_out;

  float bad = 0.0f;
  if (n_in != 5) bad = 3.0f;
  else if (in_sizes[0] != NCH * T_LEN) bad = 4.0f;
  else if (in_sizes[1] != SRM_LEN)     bad = 5.0f;
  else if (in_sizes[2] != REF_LEN)     bad = 6.0f;
  else if (in_sizes[3] != NO1 * NCH)   bad = 7.0f;
  else if (in_sizes[4] != NO1)         bad = 8.0f;
  else if (out_size != T_LEN)          bad = 9.0f;
  if (bad != 0.0f) {
    k_fill<<<T_LEN / 256, 256, 0, stream>>>(out, bad);
    return;
  }

  size_t off = 0;
  auto alloc = [&](size_t bytes) { size_t o = off; off = (off + bytes + 255) & ~(size_t)255; return o; };
  char* ws = (char*)d_ws;
  size_t oY1  = alloc((size_t)NO1 * T_LEN * 4);        // 6.55 MB (dead after k_fir1)
  size_t oP1  = alloc((size_t)NO1 * T_LEN * 4);        // 6.55 MB
  size_t oS1P = alloc((size_t)NO1 * NWORDS * 4);       // 205 KB
  size_t oP2  = alloc((size_t)T_LEN * 4);              // 262 KB
  size_t oW1T = alloc((size_t)NO1 * NCH * 4);          // 25 KB
  if (ws_size < off) {
    k_fill<<<T_LEN / 256, 256, 0, stream>>>(out, 2.0f);
    return;
  }

  float*    y1t  = (float*)(ws + oY1);
  float*    pot1 = (float*)(ws + oP1);
  unsigned* s1p  = (unsigned*)(ws + oS1P);
  float*    pot2 = (float*)(ws + oP2);
  float*    w1T  = (float*)(ws + oW1T);
  // spec buffers alias the y1t region (dead once k_fir1 completes; spec
  // kernels launch after k_fir1 in stream order). Offsets 256-aligned.
  char* yb = ws + oY1;
  unsigned* si1 = (unsigned*)(yb);                 // 51200 B
  unsigned* so1 = (unsigned*)(yb + 51200);         // 51200 B
  float*    sb1 = (float*)   (yb + 102400);        // 819200 B
  unsigned* si2 = (unsigned*)(yb + 921600);        // 2048 B
  unsigned* so2 = (unsigned*)(yb + 923648);        // 2048 B
  float*    sb2 = (float*)   (yb + 925696);        // 32768 B

  k_prep<<<1, 256, 0, stream>>>(w1, w1T);
  k_mm1<<<T_LEN / TT, 1024, 0, stream>>>(x, w1T, y1t);
  k_fir1<<<dim3(T_LEN / FTILE, NO1), 256, 0, stream>>>(y1t, srm, pot1);
  k_scan_spec<NO1, true><<<(NO1 * NBK + 63) / 64, 64, 0, stream>>>(
      pot1, refk, nullptr, s1p, si1, so1, sb1);
  k_scan_fix<NO1, true><<<NO1, 64, 0, stream>>>(pot1, refk, nullptr, s1p, si1, so1, sb1);
  k_pot2<<<T_LEN / TS, TS, 0, stream>>>(s1p, srm, w2, pot2);
  k_scan_spec<1, false><<<(NBK + 63) / 64, 64, 0, stream>>>(
      pot2, refk, out, nullptr, si2, so2, sb2);
  k_scan_fix<1, false><<<1, 64, 0, stream>>>(pot2, refk, out, nullptr, si2, so2, sb2);
}

// Round 11
// 98.649 us; speedup vs baseline: 1.0139x; 1.0139x over previous
//
#include <hip/hip_runtime.h>

// SlayerNet SNN forward, MI355X.
// y1t = w1@x [k_mm1: 16 wave-uniform c-groups, direct scalar w1, 4-deep pipe] ;
// pot1 = FIR129(y1t) [k_fir1] ; s1 = scan [bits] ;
// pot2 = FIR129(w2@s1) [linearity swap, b128 FIR] ; s2 = scan -> d_out (fp32).
// Spike scans: speculative block-parallel + exact fixup (state = last 15 spike
// bits; 15-bit mask match => bitwise-exact state).

#define T_LEN   65536
#define NCH     250
#define NO1     25
#define KTAPS   129      // taps d=0..128, eps[d] = srm[128-d]
#define PAD     128
#define SRM_LEN 257
#define REF_LEN 16
#define THETA_F 10.0f
#define LBLK    128      // scan block length (== 4 x 32-bit words)
#define NBK     512      // NBK*LBLK == T_LEN
#define WARM    128      // speculative warm-up steps
#define TT      128      // mm1 time-tile (y1t tile width)
#define FTILE   1024     // fir1 tile
#define FT2     1024     // pot2 tile
#define NWORDS  (T_LEN / 32)
#define NGRP    16       // mm1 channel groups (wave-uniform)

// One gen_spikes step. fma(s,rn,b) is bit-exact vs fadd(b,fmul(s,rn)):
// s in {0,1} makes the product exact, so single rounding = same rounding.
__device__ __forceinline__ void srm_step(float p, const float (&rn)[15], float (&b)[15],
                                         unsigned &m, float &sf_out) {
  float u = p + b[0];
  unsigned sp = (u >= THETA_F) ? 1u : 0u;
  float sf = sp ? 1.0f : 0.0f;
#pragma unroll
  for (int j = 0; j < 14; ++j) b[j] = __builtin_fmaf(sf, rn[j], b[j + 1]);
  b[14] = __fmul_rn(sf, rn[14]);
  m = (m << 1) | sp;
  sf_out = sf;
}

__global__ void k_fill(float* out, float v) {
  out[blockIdx.x * 256 + threadIdx.x] = v;
}

// K1: y1t[tile][o][p] = sum_c w1[o,c]*x[c][tile*TT+p].
// 1024 threads = 16 waves; wave g owns a contiguous channel group
// (10 groups of 16, 6 of 15); lane holds a float2 of positions (acc 50 VGPR).
// Weights: direct wave-uniform scalar loads from w1 (same values as w1T path).
// 4-deep load pipeline (named regs). Fold 16 partials via LDS, left-to-right.
__global__ __launch_bounds__(1024, 4) void k_mm1(const float* __restrict__ x,
                                                 const float* __restrict__ w1,
                                                 float* __restrict__ y1t) {
  __shared__ __align__(16) float part[NGRP][5][TT];  // 40 KB
  const int tid = threadIdx.x;
  const int lane = tid & 63;
  const int wv = __builtin_amdgcn_readfirstlane(tid >> 6);  // wave id, SGPR
  const int t0 = blockIdx.x * TT;
  const int cs = wv * 15 + (wv < 10 ? wv : 10);   // group start
  const int cn = (wv < 10) ? 16 : 15;             // group size
  float acc[NO1][2];
#pragma unroll
  for (int o = 0; o < NO1; ++o) { acc[o][0] = 0.f; acc[o][1] = 0.f; }
  const float* xp = x + (size_t)cs * T_LEN + t0 + lane * 2;

  auto ld = [&](int ci) -> float2 {   // ci wave-uniform -> scalar branch
    return (ci < cn) ? *(const float2*)(xp + (size_t)ci * T_LEN)
                     : make_float2(0.f, 0.f);
  };
  auto use = [&](int ci, float2 xv) {
    if (ci < cn) {
#pragma unroll
      for (int o = 0; o < NO1; ++o) {
        float wvv = w1[o * NCH + cs + ci];  // uniform -> s_load
        acc[o][0] = __builtin_fmaf(wvv, xv.x, acc[o][0]);
        acc[o][1] = __builtin_fmaf(wvv, xv.y, acc[o][1]);
      }
    }
  };

  float2 A0 = ld(0), A1 = ld(1), A2 = ld(2), A3 = ld(3);
  float2 B0, B1, B2, B3;
  for (int cb = 0; cb < cn; cb += 8) {
    B0 = ld(cb + 4); B1 = ld(cb + 5); B2 = ld(cb + 6); B3 = ld(cb + 7);
    use(cb + 0, A0); use(cb + 1, A1); use(cb + 2, A2); use(cb + 3, A3);
    A0 = ld(cb + 8); A1 = ld(cb + 9); A2 = ld(cb + 10); A3 = ld(cb + 11);
    use(cb + 4, B0); use(cb + 5, B1); use(cb + 6, B2); use(cb + 7, B3);
  }
  // fold in 5 rounds of 5 outputs each; left-to-right over 16 groups
  float* yb = y1t + (size_t)blockIdx.x * (NO1 * TT);
#pragma unroll
  for (int r = 0; r < 5; ++r) {
#pragma unroll
    for (int oo = 0; oo < 5; ++oo) {
      int o = r * 5 + oo;
      *(float2*)&part[wv][oo][lane * 2] = make_float2(acc[o][0], acc[o][1]);
    }
    __syncthreads();
    if (tid < 5 * (TT / 4)) {   // 160 fold threads
      int oo = tid >> 5;
      int p4 = (tid & 31) * 4;
      float4 s = *(const float4*)&part[0][oo][p4];
#pragma unroll
      for (int g = 1; g < NGRP; ++g) {
        float4 p = *(const float4*)&part[g][oo][p4];
        s.x = __fadd_rn(s.x, p.x);
        s.y = __fadd_rn(s.y, p.y);
        s.z = __fadd_rn(s.z, p.z);
        s.w = __fadd_rn(s.w, p.w);
      }
      *(float4*)&yb[(r * 5 + oo) * TT + p4] = s;
    }
    __syncthreads();
  }
}

// K2: pot1[o][t] = sum_d eps[d]*y1[o][t-d]; y1 in tiled layout [tile][o][TT].
__global__ __launch_bounds__(256, 8) void k_fir1(const float* __restrict__ y1t,
                                                 const float* __restrict__ srm,
                                                 float* __restrict__ pot1) {
  __shared__ __align__(16) float win[FTILE + PAD];
  const int tid = threadIdx.x;
  const int o = blockIdx.y;
  const int t0 = blockIdx.x * FTILE;
  for (int j = tid; j < FTILE + PAD; j += 256) {
    int g = t0 - PAD + j;
    win[j] = (g >= 0)
        ? y1t[(size_t)(g >> 7) * (NO1 * TT) + o * TT + (g & (TT - 1))] : 0.0f;
  }
  __syncthreads();
  const int base = tid * 4;
  float q0 = 0.0f, q1 = 0.0f, q2 = 0.0f, q3 = 0.0f;
  // i descending => per-output tap order d ascending (proven ordering).
#pragma unroll
  for (int i = 32; i >= 0; --i) {
    float4 v = *(const float4*)&win[base + 4 * i];
#pragma unroll
    for (int l = 3; l >= 0; --l) {
      float vl = (l == 0) ? v.x : (l == 1) ? v.y : (l == 2) ? v.z : v.w;
#pragma unroll
      for (int k = 0; k < 4; ++k) {
        int d = 128 + k - 4 * i - l;
        if (d >= 0 && d <= 128) {
          float e = srm[4 * i + l - k];  // uniform -> scalar load
          if (k == 0) q0 = __builtin_fmaf(e, vl, q0);
          else if (k == 1) q1 = __builtin_fmaf(e, vl, q1);
          else if (k == 2) q2 = __builtin_fmaf(e, vl, q2);
          else q3 = __builtin_fmaf(e, vl, q3);
        }
      }
    }
  }
  *(float4*)&pot1[(size_t)o * T_LEN + t0 + base] = make_float4(q0, q1, q2, q3);
}

// K5: pot2 = FIR129( z ),  z[t] = sum_o w2[o] * s1[o][t]  (bit-packed s1).
// z staged once in LDS, FIR via b128 reads, 4 outputs/thread (fir1 pattern).
__global__ __launch_bounds__(256) void k_pot2(const unsigned* __restrict__ s1p,
                                              const float* __restrict__ srm,
                                              const float* __restrict__ w2,
                                              float* __restrict__ pot2) {
  __shared__ __align__(16) float zs[FT2 + PAD];
  const int tid = threadIdx.x;
  const int t0 = blockIdx.x * FT2;
  for (int j = tid; j < FT2 + PAD; j += 256) {
    int g = t0 - PAD + j;
    float z = 0.0f;
    if (g >= 0) {
      int wi = g >> 5, sh = g & 31;
#pragma unroll
      for (int o = 0; o < NO1; ++o) {
        unsigned wvv = s1p[o * NWORDS + wi];
        z += ((wvv >> sh) & 1u) ? w2[o] : 0.0f;  // w2: uniform scalar load
      }
    }
    zs[j] = z;
  }
  __syncthreads();
  const int base = tid * 4;
  float q0 = 0.0f, q1 = 0.0f, q2 = 0.0f, q3 = 0.0f;
#pragma unroll
  for (int i = 32; i >= 0; --i) {
    float4 v = *(const float4*)&zs[base + 4 * i];
#pragma unroll
    for (int l = 3; l >= 0; --l) {
      float vl = (l == 0) ? v.x : (l == 1) ? v.y : (l == 2) ? v.z : v.w;
#pragma unroll
      for (int k = 0; k < 4; ++k) {
        int d = 128 + k - 4 * i - l;
        if (d >= 0 && d <= 128) {
          float e = srm[4 * i + l - k];
          if (k == 0) q0 = __builtin_fmaf(e, vl, q0);
          else if (k == 1) q1 = __builtin_fmaf(e, vl, q1);
          else if (k == 2) q2 = __builtin_fmaf(e, vl, q2);
          else q3 = __builtin_fmaf(e, vl, q3);
        }
      }
    }
  }
  *(float4*)&pot2[t0 + base] = make_float4(q0, q1, q2, q3);
}

// Speculative scan: one thread per (channel, block). WARM steps from assumed
// zero state, then LBLK emitted steps; 4-deep float4 prefetch (16 steps/iter).
template <int C, bool PACKED>
__global__ __launch_bounds__(64) void k_scan_spec(const float* __restrict__ pot,
                                                  const float* __restrict__ refk,
                                                  float* __restrict__ s,
                                                  unsigned* __restrict__ sp_,
                                                  unsigned* __restrict__ specin_m,
                                                  unsigned* __restrict__ specout_m,
                                                  float* __restrict__ specout_b) {
  int idx = blockIdx.x * 64 + threadIdx.x;
  if (idx >= C * NBK) return;
  int c = idx / NBK;
  int bb = idx - c * NBK;
  int tsr = bb * LBLK - WARM;
  float rn[15];
#pragma unroll
  for (int j = 0; j < 15; ++j) rn[j] = refk[j + 1];
  float b[15];
#pragma unroll
  for (int j = 0; j < 15; ++j) b[j] = 0.0f;
  unsigned m = 0;
  const float* prow = pot + (size_t)c * T_LEN;
  float* srow = PACKED ? nullptr : (s + (size_t)c * T_LEN);
  unsigned* srowp = PACKED ? (sp_ + (size_t)c * NWORDS) : nullptr;

  auto proc4 = [&](float4 pv, int tg, bool emit) {
    float s0, s1v, s2, s3;
    srm_step(pv.x, rn, b, m, s0);
    srm_step(pv.y, rn, b, m, s1v);
    srm_step(pv.z, rn, b, m, s2);
    srm_step(pv.w, rn, b, m, s3);
    if (emit) {
      if (PACKED) {
        if (((tg + 3) & 31) == 31) srowp[(tg - 28) >> 5] = __brev(m);
      } else {
        *(float4*)(srow + tg) = make_float4(s0, s1v, s2, s3);
      }
    }
  };

  for (int k = 0; k < WARM + LBLK; k += 16) {
    if (k == WARM) specin_m[idx] = m & 0x7FFFu;
    int t = tsr + k;
    if (t < 0) continue;   // t is a multiple of 16; never partially negative
    float4 p0 = *(const float4*)(prow + t);
    float4 p1 = *(const float4*)(prow + t + 4);
    float4 p2 = *(const float4*)(prow + t + 8);
    float4 p3 = *(const float4*)(prow + t + 12);
    const bool emit = (k >= WARM);
    proc4(p0, t, emit);
    proc4(p1, t + 4, emit);
    proc4(p2, t + 8, emit);
    proc4(p3, t + 12, emit);
  }
  specout_m[idx] = m & 0x7FFFu;
#pragma unroll
  for (int j = 0; j < 15; ++j) specout_b[idx * 16 + j] = b[j];
}

// Exact fixup: one WAVE per channel. All 8 mask-groups preloaded, ballot chain
// check => 64 blocks/iter fast path; mismatch path walks via shuffles.
template <int C, bool PACKED>
__global__ __launch_bounds__(64) void k_scan_fix(const float* __restrict__ pot,
                                                 const float* __restrict__ refk,
                                                 float* __restrict__ s,
                                                 unsigned* __restrict__ sp_,
                                                 const unsigned* __restrict__ specin_m,
                                                 const unsigned* __restrict__ specout_m,
                                                 const float* __restrict__ specout_b) {
  const int c = blockIdx.x;
  const int lane = threadIdx.x;
  float rn[15];
#pragma unroll
  for (int j = 0; j < 15; ++j) rn[j] = refk[j + 1];
  float b[15];
#pragma unroll
  for (int j = 0; j < 15; ++j) b[j] = 0.0f;
  unsigned m = 0;
  bool haveB = true;
  const float* prow = pot + (size_t)c * T_LEN;
  float* srow = PACKED ? nullptr : (s + (size_t)c * T_LEN);
  unsigned* srowp = PACKED ? (sp_ + (size_t)c * NWORDS) : nullptr;
  unsigned prev_last = 0;

  unsigned siv[NBK / 64], sov[NBK / 64];
#pragma unroll
  for (int g = 0; g < NBK / 64; ++g) {
    siv[g] = specin_m[c * NBK + g * 64 + lane];
    sov[g] = specout_m[c * NBK + g * 64 + lane];
  }
#pragma unroll
  for (int g = 0; g < NBK / 64; ++g) {
    const unsigned si = siv[g];
    const unsigned so = sov[g];
    unsigned so_prev = __shfl_up(so, 1);
    if (lane == 0) so_prev = prev_last;
    const unsigned long long flags = __ballot(si == so_prev);
    prev_last = __shfl(so, 63);
    const unsigned si0 = __shfl(si, 0);
    if (flags == ~0ull && (m & 0x7FFFu) == si0) {
      m = prev_last;
      haveB = false;
      continue;
    }
    for (int r = 0; r < 64; ++r) {
      const unsigned sir = __shfl(si, r);
      const unsigned sor = __shfl(so, r);
      if ((m & 0x7FFFu) == sir) {
        m = sor;
        haveB = false;
      } else {
        const int bbr = g * 64 + r;  // bbr>=1: block 0 entry mask 0 always matches
        if (!haveB) {
          const int pb = (c * NBK + bbr - 1) * 16;
#pragma unroll
          for (int q2 = 0; q2 < 15; ++q2) b[q2] = specout_b[pb + q2];
          haveB = true;
        }
        const int t0 = bbr * LBLK;
        for (int t = t0; t < t0 + LBLK; t += 4) {
          float4 pv = *(const float4*)(prow + t);
          float s0, s1v, s2, s3;
          srm_step(pv.x, rn, b, m, s0);
          srm_step(pv.y, rn, b, m, s1v);
          srm_step(pv.z, rn, b, m, s2);
          srm_step(pv.w, rn, b, m, s3);
          if (PACKED) {
            if ((((t + 3) & 31) == 31) && lane == 0) srowp[(t - 28) >> 5] = __brev(m);
          } else {
            if (lane == 0) *(float4*)(srow + t) = make_float4(s0, s1v, s2, s3);
          }
        }
        haveB = true;
      }
    }
  }
}

extern "C" void kernel_launch(void* const* d_in, const int* in_sizes, int n_in,
                              void* d_out, int out_size, void* d_ws, size_t ws_size,
                              hipStream_t stream) {
  const float* x    = (const float*)d_in[0];  // 250*65536
  const float* srm  = (const float*)d_in[1];  // 257
  const float* refk = (const float*)d_in[2];  // 16
  const float* w1   = (const float*)d_in[3];  // 25*250
  const float* w2   = (const float*)d_in[4];  // 25
  float* out = (float*)d_out;

  float bad = 0.0f;
  if (n_in != 5) bad = 3.0f;
  else if (in_sizes[0] != NCH * T_LEN) bad = 4.0f;
  else if (in_sizes[1] != SRM_LEN)     bad = 5.0f;
  else if (in_sizes[2] != REF_LEN)     bad = 6.0f;
  else if (in_sizes[3] != NO1 * NCH)   bad = 7.0f;
  else if (in_sizes[4] != NO1)         bad = 8.0f;
  else if (out_size != T_LEN)          bad = 9.0f;
  if (bad != 0.0f) {
    k_fill<<<T_LEN / 256, 256, 0, stream>>>(out, bad);
    return;
  }

  size_t off = 0;
  auto alloc = [&](size_t bytes) { size_t o = off; off = (off + bytes + 255) & ~(size_t)255; return o; };
  char* ws = (char*)d_ws;
  size_t oY1  = alloc((size_t)NO1 * T_LEN * 4);        // 6.55 MB (dead after k_fir1)
  size_t oP1  = alloc((size_t)NO1 * T_LEN * 4);        // 6.55 MB
  size_t oS1P = alloc((size_t)NO1 * NWORDS * 4);       // 205 KB
  size_t oP2  = alloc((size_t)T_LEN * 4);              // 262 KB
  if (ws_size < off) {
    k_fill<<<T_LEN / 256, 256, 0, stream>>>(out, 2.0f);
    return;
  }

  float*    y1t  = (float*)(ws + oY1);
  float*    pot1 = (float*)(ws + oP1);
  unsigned* s1p  = (unsigned*)(ws + oS1P);
  float*    pot2 = (float*)(ws + oP2);
  // spec buffers alias the y1t region (dead once k_fir1 completes; spec
  // kernels launch after k_fir1 in stream order). Offsets 256-aligned.
  char* yb = ws + oY1;
  unsigned* si1 = (unsigned*)(yb);                 // 51200 B
  unsigned* so1 = (unsigned*)(yb + 51200);         // 51200 B
  float*    sb1 = (float*)   (yb + 102400);        // 819200 B
  unsigned* si2 = (unsigned*)(yb + 921600);        // 2048 B
  unsigned* so2 = (unsigned*)(yb + 923648);        // 2048 B
  float*    sb2 = (float*)   (yb + 925696);        // 32768 B

  k_mm1<<<T_LEN / TT, 1024, 0, stream>>>(x, w1, y1t);
  k_fir1<<<dim3(T_LEN / FTILE, NO1), 256, 0, stream>>>(y1t, srm, pot1);
  k_scan_spec<NO1, true><<<(NO1 * NBK + 63) / 64, 64, 0, stream>>>(
      pot1, refk, nullptr, s1p, si1, so1, sb1);
  k_scan_fix<NO1, true><<<NO1, 64, 0, stream>>>(pot1, refk, nullptr, s1p, si1, so1, sb1);
  k_pot2<<<T_LEN / FT2, 256, 0, stream>>>(s1p, srm, w2, pot2);
  k_scan_spec<1, false><<<(NBK + 63) / 64, 64, 0, stream>>>(
      pot2, refk, out, nullptr, si2, so2, sb2);
  k_scan_fix<1, false><<<1, 64, 0, stream>>>(pot2, refk, out, nullptr, si2, so2, sb2);
}

// Round 12
// 94.425 us; speedup vs baseline: 1.0593x; 1.0447x over previous
//
#include <hip/hip_runtime.h>

// SlayerNet SNN forward, MI355X.
// y1t = w1@x [k_mm1: 8 wave-uniform c-groups padded to 32 slots, zero-weight
//   dummies, straight-line 4-deep pipeline, scalar-pipe weights] ;
// pot1 = FIR129(y1t) [k_fir1] ; s1 = scan [bits] ;
// pot2 = FIR129(w2@s1) [linearity swap, b128 FIR] ; s2 = scan -> d_out (fp32).
// Spike scans: speculative block-parallel + exact fixup (state = last 15 spike
// bits; 15-bit mask match => bitwise-exact state).

#define T_LEN   65536
#define NCH     250
#define NO1     25
#define KTAPS   129      // taps d=0..128, eps[d] = srm[128-d]
#define PAD     128
#define SRM_LEN 257
#define REF_LEN 16
#define THETA_F 10.0f
#define LBLK    128      // scan block length (== 4 x 32-bit words)
#define NBK     512      // NBK*LBLK == T_LEN
#define WARM    128      // speculative warm-up steps
#define TT      128      // mm1 time-tile (y1t tile width)
#define FTILE   1024     // fir1 tile
#define FT2     1024     // pot2 tile
#define NWORDS  (T_LEN / 32)
#define NGRP    8        // mm1 channel groups (wave-uniform), 32 slots each

// One gen_spikes step. fma(s,rn,b) is bit-exact vs fadd(b,fmul(s,rn)):
// s in {0,1} makes the product exact, so single rounding = same rounding.
__device__ __forceinline__ void srm_step(float p, const float (&rn)[15], float (&b)[15],
                                         unsigned &m, float &sf_out) {
  float u = p + b[0];
  unsigned sp = (u >= THETA_F) ? 1u : 0u;
  float sf = sp ? 1.0f : 0.0f;
#pragma unroll
  for (int j = 0; j < 14; ++j) b[j] = __builtin_fmaf(sf, rn[j], b[j + 1]);
  b[14] = __fmul_rn(sf, rn[14]);
  m = (m << 1) | sp;
  sf_out = sf;
}

__global__ void k_fill(float* out, float v) {
  out[blockIdx.x * 256 + threadIdx.x] = v;
}

// Build padded grouped weights: wg[g][ci][o] = w1[o][cs_g+ci] (ci<cn_g) else 0.
__global__ __launch_bounds__(256) void k_prep2(const float* __restrict__ w1,
                                               float* __restrict__ wg) {
  for (int i = threadIdx.x; i < NGRP * 32 * NO1; i += 256) {
    int g = i / (32 * NO1);
    int r = i - g * 32 * NO1;
    int ci = r / NO1;
    int o = r - ci * NO1;
    int cs = g * 31 + (g < 2 ? g : 2);
    int cn = (g < 2) ? 32 : 31;
    wg[i] = (ci < cn) ? w1[o * NCH + cs + ci] : 0.0f;
  }
}

template <int CI>
__device__ __forceinline__ void use_slot(const float* __restrict__ wgp,
                                         float (&acc)[NO1][2], float2 xv) {
#pragma unroll
  for (int o = 0; o < NO1; ++o) {
    float wvv = wgp[CI * NO1 + o];   // uniform -> s_load (dwordx16 batches)
    acc[o][0] = __builtin_fmaf(wvv, xv.x, acc[o][0]);
    acc[o][1] = __builtin_fmaf(wvv, xv.y, acc[o][1]);
  }
}

// K1: y1t[tile][o][p] = sum_c w1[o,c]*x[c][tile*TT+p].
// 512 threads = 8 waves; wave g owns channel group g (32 padded slots).
// Lane holds a float2 of positions. Straight-line 4-deep load pipeline,
// all acc indices compile-time (no spill). Fold 8 partials via LDS.
__global__ __launch_bounds__(512, 6) void k_mm1(const float* __restrict__ x,
                                                const float* __restrict__ wg,
                                                float* __restrict__ y1t) {
  __shared__ __align__(16) float part[NGRP][5][TT];  // 20 KB
  const int tid = threadIdx.x;
  const int lane = tid & 63;
  const int wv = __builtin_amdgcn_readfirstlane(tid >> 6);  // wave id 0..7
  const int t0 = blockIdx.x * TT;
  const int cs = wv * 31 + (wv < 2 ? wv : 2);
  const int cn = (wv < 2) ? 32 : 31;
  const int s31 = cn - 1;            // slot 31 channel offset (clamped, w=0)
  const float* wgp = wg + wv * (32 * NO1);           // SGPR base
  const float* xp = x + (size_t)cs * T_LEN + t0 + lane * 2;
  float acc[NO1][2];
#pragma unroll
  for (int o = 0; o < NO1; ++o) { acc[o][0] = 0.f; acc[o][1] = 0.f; }

#define LDX(ci) (*(const float2*)(xp + (size_t)(ci) * T_LEN))
  float2 A0, A1, A2, A3, B0, B1, B2, B3;
  A0 = LDX(0);  A1 = LDX(1);  A2 = LDX(2);  A3 = LDX(3);
  B0 = LDX(4);  B1 = LDX(5);  B2 = LDX(6);  B3 = LDX(7);
  use_slot<0>(wgp, acc, A0);  use_slot<1>(wgp, acc, A1);
  use_slot<2>(wgp, acc, A2);  use_slot<3>(wgp, acc, A3);
  A0 = LDX(8);  A1 = LDX(9);  A2 = LDX(10); A3 = LDX(11);
  use_slot<4>(wgp, acc, B0);  use_slot<5>(wgp, acc, B1);
  use_slot<6>(wgp, acc, B2);  use_slot<7>(wgp, acc, B3);
  B0 = LDX(12); B1 = LDX(13); B2 = LDX(14); B3 = LDX(15);
  use_slot<8>(wgp, acc, A0);  use_slot<9>(wgp, acc, A1);
  use_slot<10>(wgp, acc, A2); use_slot<11>(wgp, acc, A3);
  A0 = LDX(16); A1 = LDX(17); A2 = LDX(18); A3 = LDX(19);
  use_slot<12>(wgp, acc, B0); use_slot<13>(wgp, acc, B1);
  use_slot<14>(wgp, acc, B2); use_slot<15>(wgp, acc, B3);
  B0 = LDX(20); B1 = LDX(21); B2 = LDX(22); B3 = LDX(23);
  use_slot<16>(wgp, acc, A0); use_slot<17>(wgp, acc, A1);
  use_slot<18>(wgp, acc, A2); use_slot<19>(wgp, acc, A3);
  A0 = LDX(24); A1 = LDX(25); A2 = LDX(26); A3 = LDX(27);
  use_slot<20>(wgp, acc, B0); use_slot<21>(wgp, acc, B1);
  use_slot<22>(wgp, acc, B2); use_slot<23>(wgp, acc, B3);
  B0 = LDX(28); B1 = LDX(29); B2 = LDX(30); B3 = LDX(s31);
  use_slot<24>(wgp, acc, A0); use_slot<25>(wgp, acc, A1);
  use_slot<26>(wgp, acc, A2); use_slot<27>(wgp, acc, A3);
  use_slot<28>(wgp, acc, B0); use_slot<29>(wgp, acc, B1);
  use_slot<30>(wgp, acc, B2); use_slot<31>(wgp, acc, B3);
#undef LDX

  // fold in 5 rounds of 5 outputs each; left-to-right over 8 groups
  float* yb = y1t + (size_t)blockIdx.x * (NO1 * TT);
#pragma unroll
  for (int r = 0; r < 5; ++r) {
#pragma unroll
    for (int oo = 0; oo < 5; ++oo) {
      int o = r * 5 + oo;
      *(float2*)&part[wv][oo][lane * 2] = make_float2(acc[o][0], acc[o][1]);
    }
    __syncthreads();
    if (tid < 5 * (TT / 4)) {   // 160 fold threads
      int oo = tid >> 5;
      int p4 = (tid & 31) * 4;
      float4 s = *(const float4*)&part[0][oo][p4];
#pragma unroll
      for (int g = 1; g < NGRP; ++g) {
        float4 p = *(const float4*)&part[g][oo][p4];
        s.x = __fadd_rn(s.x, p.x);
        s.y = __fadd_rn(s.y, p.y);
        s.z = __fadd_rn(s.z, p.z);
        s.w = __fadd_rn(s.w, p.w);
      }
      *(float4*)&yb[(r * 5 + oo) * TT + p4] = s;
    }
    __syncthreads();
  }
}

// K2: pot1[o][t] = sum_d eps[d]*y1[o][t-d]; y1 in tiled layout [tile][o][TT].
__global__ __launch_bounds__(256, 8) void k_fir1(const float* __restrict__ y1t,
                                                 const float* __restrict__ srm,
                                                 float* __restrict__ pot1) {
  __shared__ __align__(16) float win[FTILE + PAD];
  const int tid = threadIdx.x;
  const int o = blockIdx.y;
  const int t0 = blockIdx.x * FTILE;
  for (int j = tid; j < FTILE + PAD; j += 256) {
    int g = t0 - PAD + j;
    win[j] = (g >= 0)
        ? y1t[(size_t)(g >> 7) * (NO1 * TT) + o * TT + (g & (TT - 1))] : 0.0f;
  }
  __syncthreads();
  const int base = tid * 4;
  float q0 = 0.0f, q1 = 0.0f, q2 = 0.0f, q3 = 0.0f;
  // i descending => per-output tap order d ascending (proven ordering).
#pragma unroll
  for (int i = 32; i >= 0; --i) {
    float4 v = *(const float4*)&win[base + 4 * i];
#pragma unroll
    for (int l = 3; l >= 0; --l) {
      float vl = (l == 0) ? v.x : (l == 1) ? v.y : (l == 2) ? v.z : v.w;
#pragma unroll
      for (int k = 0; k < 4; ++k) {
        int d = 128 + k - 4 * i - l;
        if (d >= 0 && d <= 128) {
          float e = srm[4 * i + l - k];  // uniform -> scalar load
          if (k == 0) q0 = __builtin_fmaf(e, vl, q0);
          else if (k == 1) q1 = __builtin_fmaf(e, vl, q1);
          else if (k == 2) q2 = __builtin_fmaf(e, vl, q2);
          else q3 = __builtin_fmaf(e, vl, q3);
        }
      }
    }
  }
  *(float4*)&pot1[(size_t)o * T_LEN + t0 + base] = make_float4(q0, q1, q2, q3);
}

// K5: pot2 = FIR129( z ),  z[t] = sum_o w2[o] * s1[o][t]  (bit-packed s1).
// z staged once in LDS, FIR via b128 reads, 4 outputs/thread (fir1 pattern).
__global__ __launch_bounds__(256) void k_pot2(const unsigned* __restrict__ s1p,
                                              const float* __restrict__ srm,
                                              const float* __restrict__ w2,
                                              float* __restrict__ pot2) {
  __shared__ __align__(16) float zs[FT2 + PAD];
  const int tid = threadIdx.x;
  const int t0 = blockIdx.x * FT2;
  for (int j = tid; j < FT2 + PAD; j += 256) {
    int g = t0 - PAD + j;
    float z = 0.0f;
    if (g >= 0) {
      int wi = g >> 5, sh = g & 31;
#pragma unroll
      for (int o = 0; o < NO1; ++o) {
        unsigned wvv = s1p[o * NWORDS + wi];
        z += ((wvv >> sh) & 1u) ? w2[o] : 0.0f;  // w2: uniform scalar load
      }
    }
    zs[j] = z;
  }
  __syncthreads();
  const int base = tid * 4;
  float q0 = 0.0f, q1 = 0.0f, q2 = 0.0f, q3 = 0.0f;
#pragma unroll
  for (int i = 32; i >= 0; --i) {
    float4 v = *(const float4*)&zs[base + 4 * i];
#pragma unroll
    for (int l = 3; l >= 0; --l) {
      float vl = (l == 0) ? v.x : (l == 1) ? v.y : (l == 2) ? v.z : v.w;
#pragma unroll
      for (int k = 0; k < 4; ++k) {
        int d = 128 + k - 4 * i - l;
        if (d >= 0 && d <= 128) {
          float e = srm[4 * i + l - k];
          if (k == 0) q0 = __builtin_fmaf(e, vl, q0);
          else if (k == 1) q1 = __builtin_fmaf(e, vl, q1);
          else if (k == 2) q2 = __builtin_fmaf(e, vl, q2);
          else q3 = __builtin_fmaf(e, vl, q3);
        }
      }
    }
  }
  *(float4*)&pot2[t0 + base] = make_float4(q0, q1, q2, q3);
}

// Speculative scan: one thread per (channel, block). WARM steps from assumed
// zero state, then LBLK emitted steps; 4-deep float4 prefetch (16 steps/iter).
template <int C, bool PACKED>
__global__ __launch_bounds__(64) void k_scan_spec(const float* __restrict__ pot,
                                                  const float* __restrict__ refk,
                                                  float* __restrict__ s,
                                                  unsigned* __restrict__ sp_,
                                                  unsigned* __restrict__ specin_m,
                                                  unsigned* __restrict__ specout_m,
                                                  float* __restrict__ specout_b) {
  int idx = blockIdx.x * 64 + threadIdx.x;
  if (idx >= C * NBK) return;
  int c = idx / NBK;
  int bb = idx - c * NBK;
  int tsr = bb * LBLK - WARM;
  float rn[15];
#pragma unroll
  for (int j = 0; j < 15; ++j) rn[j] = refk[j + 1];
  float b[15];
#pragma unroll
  for (int j = 0; j < 15; ++j) b[j] = 0.0f;
  unsigned m = 0;
  const float* prow = pot + (size_t)c * T_LEN;
  float* srow = PACKED ? nullptr : (s + (size_t)c * T_LEN);
  unsigned* srowp = PACKED ? (sp_ + (size_t)c * NWORDS) : nullptr;

  auto proc4 = [&](float4 pv, int tg, bool emit) {
    float s0, s1v, s2, s3;
    srm_step(pv.x, rn, b, m, s0);
    srm_step(pv.y, rn, b, m, s1v);
    srm_step(pv.z, rn, b, m, s2);
    srm_step(pv.w, rn, b, m, s3);
    if (emit) {
      if (PACKED) {
        if (((tg + 3) & 31) == 31) srowp[(tg - 28) >> 5] = __brev(m);
      } else {
        *(float4*)(srow + tg) = make_float4(s0, s1v, s2, s3);
      }
    }
  };

  for (int k = 0; k < WARM + LBLK; k += 16) {
    if (k == WARM) specin_m[idx] = m & 0x7FFFu;
    int t = tsr + k;
    if (t < 0) continue;   // t is a multiple of 16; never partially negative
    float4 p0 = *(const float4*)(prow + t);
    float4 p1 = *(const float4*)(prow + t + 4);
    float4 p2 = *(const float4*)(prow + t + 8);
    float4 p3 = *(const float4*)(prow + t + 12);
    const bool emit = (k >= WARM);
    proc4(p0, t, emit);
    proc4(p1, t + 4, emit);
    proc4(p2, t + 8, emit);
    proc4(p3, t + 12, emit);
  }
  specout_m[idx] = m & 0x7FFFu;
#pragma unroll
  for (int j = 0; j < 15; ++j) specout_b[idx * 16 + j] = b[j];
}

// Exact fixup: one WAVE per channel. All 8 mask-groups preloaded, ballot chain
// check => 64 blocks/iter fast path; mismatch path walks via shuffles.
template <int C, bool PACKED>
__global__ __launch_bounds__(64) void k_scan_fix(const float* __restrict__ pot,
                                                 const float* __restrict__ refk,
                                                 float* __restrict__ s,
                                                 unsigned* __restrict__ sp_,
                                                 const unsigned* __restrict__ specin_m,
                                                 const unsigned* __restrict__ specout_m,
                                                 const float* __restrict__ specout_b) {
  const int c = blockIdx.x;
  const int lane = threadIdx.x;
  float rn[15];
#pragma unroll
  for (int j = 0; j < 15; ++j) rn[j] = refk[j + 1];
  float b[15];
#pragma unroll
  for (int j = 0; j < 15; ++j) b[j] = 0.0f;
  unsigned m = 0;
  bool haveB = true;
  const float* prow = pot + (size_t)c * T_LEN;
  float* srow = PACKED ? nullptr : (s + (size_t)c * T_LEN);
  unsigned* srowp = PACKED ? (sp_ + (size_t)c * NWORDS) : nullptr;
  unsigned prev_last = 0;

  unsigned siv[NBK / 64], sov[NBK / 64];
#pragma unroll
  for (int g = 0; g < NBK / 64; ++g) {
    siv[g] = specin_m[c * NBK + g * 64 + lane];
    sov[g] = specout_m[c * NBK + g * 64 + lane];
  }
#pragma unroll
  for (int g = 0; g < NBK / 64; ++g) {
    const unsigned si = siv[g];
    const unsigned so = sov[g];
    unsigned so_prev = __shfl_up(so, 1);
    if (lane == 0) so_prev = prev_last;
    const unsigned long long flags = __ballot(si == so_prev);
    prev_last = __shfl(so, 63);
    const unsigned si0 = __shfl(si, 0);
    if (flags == ~0ull && (m & 0x7FFFu) == si0) {
      m = prev_last;
      haveB = false;
      continue;
    }
    for (int r = 0; r < 64; ++r) {
      const unsigned sir = __shfl(si, r);
      const unsigned sor = __shfl(so, r);
      if ((m & 0x7FFFu) == sir) {
        m = sor;
        haveB = false;
      } else {
        const int bbr = g * 64 + r;  // bbr>=1: block 0 entry mask 0 always matches
        if (!haveB) {
          const int pb = (c * NBK + bbr - 1) * 16;
#pragma unroll
          for (int q2 = 0; q2 < 15; ++q2) b[q2] = specout_b[pb + q2];
          haveB = true;
        }
        const int t0 = bbr * LBLK;
        for (int t = t0; t < t0 + LBLK; t += 4) {
          float4 pv = *(const float4*)(prow + t);
          float s0, s1v, s2, s3;
          srm_step(pv.x, rn, b, m, s0);
          srm_step(pv.y, rn, b, m, s1v);
          srm_step(pv.z, rn, b, m, s2);
          srm_step(pv.w, rn, b, m, s3);
          if (PACKED) {
            if ((((t + 3) & 31) == 31) && lane == 0) srowp[(t - 28) >> 5] = __brev(m);
          } else {
            if (lane == 0) *(float4*)(srow + t) = make_float4(s0, s1v, s2, s3);
          }
        }
        haveB = true;
      }
    }
  }
}

extern "C" void kernel_launch(void* const* d_in, const int* in_sizes, int n_in,
                              void* d_out, int out_size, void* d_ws, size_t ws_size,
                              hipStream_t stream) {
  const float* x    = (const float*)d_in[0];  // 250*65536
  const float* srm  = (const float*)d_in[1];  // 257
  const float* refk = (const float*)d_in[2];  // 16
  const float* w1   = (const float*)d_in[3];  // 25*250
  const float* w2   = (const float*)d_in[4];  // 25
  float* out = (float*)d_out;

  float bad = 0.0f;
  if (n_in != 5) bad = 3.0f;
  else if (in_sizes[0] != NCH * T_LEN) bad = 4.0f;
  else if (in_sizes[1] != SRM_LEN)     bad = 5.0f;
  else if (in_sizes[2] != REF_LEN)     bad = 6.0f;
  else if (in_sizes[3] != NO1 * NCH)   bad = 7.0f;
  else if (in_sizes[4] != NO1)         bad = 8.0f;
  else if (out_size != T_LEN)          bad = 9.0f;
  if (bad != 0.0f) {
    k_fill<<<T_LEN / 256, 256, 0, stream>>>(out, bad);
    return;
  }

  size_t off = 0;
  auto alloc = [&](size_t bytes) { size_t o = off; off = (off + bytes + 255) & ~(size_t)255; return o; };
  char* ws = (char*)d_ws;
  size_t oY1  = alloc((size_t)NO1 * T_LEN * 4);        // 6.55 MB (dead after k_fir1)
  size_t oP1  = alloc((size_t)NO1 * T_LEN * 4);        // 6.55 MB
  size_t oS1P = alloc((size_t)NO1 * NWORDS * 4);       // 205 KB
  size_t oP2  = alloc((size_t)T_LEN * 4);              // 262 KB
  size_t oWG  = alloc((size_t)NGRP * 32 * NO1 * 4);    // 25.6 KB
  if (ws_size < off) {
    k_fill<<<T_LEN / 256, 256, 0, stream>>>(out, 2.0f);
    return;
  }

  float*    y1t  = (float*)(ws + oY1);
  float*    pot1 = (float*)(ws + oP1);
  unsigned* s1p  = (unsigned*)(ws + oS1P);
  float*    pot2 = (float*)(ws + oP2);
  float*    wg   = (float*)(ws + oWG);
  // spec buffers alias the y1t region (dead once k_fir1 completes; spec
  // kernels launch after k_fir1 in stream order). Offsets 256-aligned.
  char* yb = ws + oY1;
  unsigned* si1 = (unsigned*)(yb);                 // 51200 B
  unsigned* so1 = (unsigned*)(yb + 51200);         // 51200 B
  float*    sb1 = (float*)   (yb + 102400);        // 819200 B
  unsigned* si2 = (unsigned*)(yb + 921600);        // 2048 B
  unsigned* so2 = (unsigned*)(yb + 923648);        // 2048 B
  float*    sb2 = (float*)   (yb + 925696);        // 32768 B

  k_prep2<<<1, 256, 0, stream>>>(w1, wg);
  k_mm1<<<T_LEN / TT, 512, 0, stream>>>(x, wg, y1t);
  k_fir1<<<dim3(T_LEN / FTILE, NO1), 256, 0, stream>>>(y1t, srm, pot1);
  k_scan_spec<NO1, true><<<(NO1 * NBK + 63) / 64, 64, 0, stream>>>(
      pot1, refk, nullptr, s1p, si1, so1, sb1);
  k_scan_fix<NO1, true><<<NO1, 64, 0, stream>>>(pot1, refk, nullptr, s1p, si1, so1, sb1);
  k_pot2<<<T_LEN / FT2, 256, 0, stream>>>(s1p, srm, w2, pot2);
  k_scan_spec<1, false><<<(NBK + 63) / 64, 64, 0, stream>>>(
      pot2, refk, out, nullptr, si2, so2, sb2);
  k_scan_fix<1, false><<<1, 64, 0, stream>>>(pot2, refk, out, nullptr, si2, so2, sb2);
}